// Round 9
// baseline (209.792 us; speedup 1.0000x reference)
//
#include <hip/hip_runtime.h>
#include <hip/hip_bf16.h>
#include <math.h>

#define NB 16      // batch
#define CS 80      // spec channels
#define T1 1000    // mel frames
#define CT 512     // text channels
#define T2 200     // phonemes
#define CA 80      // attn channels
#define GD 256     // speaker dim
#define C2T 1024   // 2*Ct
#define C2S 160    // 2*Cs
#define TEMP_F 0.0005f
#define ENC_STR 96   // padded row stride for k_encT/q_encT (zero-filled 80..95)
#define TPK 258      // padded t-rows for xkTp (row = t+1, guards zeroed)
#define TPQ 1027     // padded t-rows for xqTp

typedef __attribute__((ext_vector_type(8))) short short8;
typedef __attribute__((ext_vector_type(4))) float floatx4;

// fp32 -> bf16 bits, round-to-nearest-even
__device__ __forceinline__ short f2bf(float x) {
    unsigned u = __builtin_bit_cast(unsigned, x);
    unsigned r = (u + 0x7fffu + ((u >> 16) & 1u)) >> 16;
    return (short)r;
}

// ---------------------------------------------------------------------------
// weight pack into MFMA A-fragment-major layout:
//   wp[((co16*KW + k)*NC32 + ci32)*512 + lane*8 + j]
//   co = co16*16 + (lane&15), ci = ci32*32 + (lane>>4)*8 + j
// ---------------------------------------------------------------------------
template <int COUT, int CIN, int KW, int COP, int CINP>
__device__ __forceinline__ void wpack_body(const float* __restrict__ w,
                                           short* __restrict__ wp, int bid) {
    constexpr int NC32 = CINP / 32;
    constexpr int NFRAG = (COP / 16) * KW * NC32;
    int gid = bid * 256 + threadIdx.x;
    int frag = gid >> 6, lane = gid & 63;
    if (frag >= NFRAG) return;
    int co16 = frag / (KW * NC32), rem = frag - co16 * (KW * NC32);
    int k = rem / NC32, ci32 = rem - k * NC32;
    int co = co16 * 16 + (lane & 15);
    int ci = ci32 * 32 + (lane >> 4) * 8;
    short8 v;
#pragma unroll
    for (int j = 0; j < 8; j++) {
        float f = 0.f;
        if (co < COUT && ci + j < CIN) f = w[((size_t)co * CIN + ci + j) * KW + k];
        v[j] = f2bf(f);
    }
    *(short8*)(wp + (size_t)frag * 512 + lane * 8) = v;
}

// ---------------------------------------------------------------------------
// addspkT with inlined speaker projection, writing halo-padded layout:
// in fp32 [b][C][T] + (g[b]·w_spk[c]+b_spk[c]) -> out bf16 [b][TP][CP], row=t+1
// ---------------------------------------------------------------------------
template <int C, int T, int CP, int TP>
__device__ __forceinline__ void addspkT_body(const float* __restrict__ in,
                                             const float* __restrict__ g,
                                             const float* __restrict__ w_spk,
                                             const float* __restrict__ b_spk,
                                             short* __restrict__ outT,
                                             float* sm, int bx, int by, int b) {
    float* spkS = sm;          // 32
    float* S = sm + 32;        // 32*65
    const int t0 = bx * 64, c0 = by * 32;
    const int tid = threadIdx.x;
    int cl = tid >> 3, part = tid & 7;
    int c = c0 + cl;
    float s = 0.f;
    if (c < C) {
        const float* wr = w_spk + (size_t)c * GD;
        const float* gr = g + b * GD;
        int j0 = part * 32;
#pragma unroll
        for (int j = 0; j < 32; j++) s += gr[j0 + j] * wr[j0 + j];
    }
    s += __shfl_xor(s, 1, 64); s += __shfl_xor(s, 2, 64); s += __shfl_xor(s, 4, 64);
    if (part == 0) spkS[cl] = s + ((c < C) ? b_spk[c] : 0.f);
    __syncthreads();
    for (int i = tid; i < 32 * 64; i += 256) {
        int cll = i >> 6, tl = i & 63;
        int gc = c0 + cll, gt = t0 + tl;
        float v = 0.f;
        if (gc < C && gt < T) v = in[((size_t)b * C + gc) * T + gt] + spkS[cll];
        S[cll * 65 + tl] = v;
    }
    __syncthreads();
    for (int i = tid; i < 64 * 32; i += 256) {
        int tl = i >> 5, cll = i & 31;
        int gt = t0 + tl, gc = c0 + cll;
        if (gc < CP && gt < T)   // value is 0 for gc in [C,CP)
            outT[((size_t)b * TP + gt + 1) * CP + gc] = f2bf(S[cll * 65 + tl]);
    }
}

// ---------------------------------------------------------------------------
// P: one dispatch for all prep (packs + padded transposes + guard zero-fill)
// ---------------------------------------------------------------------------
__global__ __launch_bounds__(256) void prep_kernel(
    const float* __restrict__ keys, const float* __restrict__ queries, const float* __restrict__ g,
    const float* __restrict__ wk1, const float* __restrict__ wq1, const float* __restrict__ wk2,
    const float* __restrict__ wq2, const float* __restrict__ wq3,
    const float* __restrict__ w_kspk, const float* __restrict__ b_kspk,
    const float* __restrict__ w_qspk, const float* __restrict__ b_qspk,
    short* __restrict__ wk1p, short* __restrict__ wq1p, short* __restrict__ wk2p,
    short* __restrict__ wq2p, short* __restrict__ wq3p,
    short* __restrict__ xkTp, short* __restrict__ xqTp) {
    __shared__ float sm[32 + 32 * 65];
    int bid = blockIdx.x;
    if (bid < 768) { wpack_body<C2T, CT, 3, C2T, CT>(wk1, wk1p, bid); return; }
    bid -= 768;
    if (bid < 27) { wpack_body<C2S, CS, 3, 192, 96>(wq1, wq1p, bid); return; }
    bid -= 27;
    if (bid < 40) { wpack_body<CA, C2T, 1, 80, 1024>(wk2, wk2p, bid); return; }
    bid -= 40;
    if (bid < 7) { wpack_body<CA, C2S, 1, 80, 160>(wq2, wq2p, bid); return; }
    bid -= 7;
    if (bid < 4) { wpack_body<CA, CS, 1, 80, 96>(wq3, wq3p, bid); return; }
    bid -= 4;
    if (bid < 1024) {
        int bx = bid & 3, by = (bid >> 2) & 15, b = bid >> 6;
        addspkT_body<CT, T2, 512, TPK>(keys, g, w_kspk, b_kspk, xkTp, sm, bx, by, b);
        return;
    }
    bid -= 1024;
    if (bid < 768) {
        int bx = bid & 15, by = (bid >> 4) % 3, b = bid / 48;
        addspkT_body<CS, T1, ENC_STR, TPQ>(queries, g, w_qspk, b_qspk, xqTp, sm, bx, by, b);
        return;
    }
    bid -= 768;
    if (bid < 32) {
        // zero xkTp guard rows: per b, row 0 and rows 201..257 (58 rows x 512 shorts)
        const uint4 z = {0u, 0u, 0u, 0u};
        for (int i = bid * 256 + threadIdx.x; i < 16 * 3712; i += 32 * 256) {
            int b = i / 3712, r = i - b * 3712;
            int r64 = r >> 6, c8 = r & 63;
            int row = (r64 == 0) ? 0 : 200 + r64;          // 0, 201..257
            *(uint4*)(xkTp + ((size_t)b * TPK + row) * 512 + c8 * 8) = z;
        }
        return;
    }
    bid -= 32;
    {
        // zero xqTp guard rows: per b, row 0 and rows 1001..1026 (27 rows x 96 shorts)
        const uint4 z = {0u, 0u, 0u, 0u};
        for (int i = bid * 256 + threadIdx.x; i < 16 * 324; i += 4 * 256) {
            int b = i / 324, r = i - b * 324;
            int r12 = r / 12, c8 = r - r12 * 12;
            int row = (r12 == 0) ? 0 : 1000 + r12;         // 0, 1001..1026
            *(uint4*)(xqTp + ((size_t)b * TPQ + row) * ENC_STR + c8 * 8) = z;
        }
    }
}

// ---------------------------------------------------------------------------
// LDS-free conv3-as-GEMM: both A (weights) and B (X rows) fragments read
// directly from global (L1/L2-resident; halo handled by zero guard rows).
// Block 64co x 128t, 4 t-stacked waves (64co x 32t each).  16x16x32 bf16 MFMA:
//   A lane m=l16(co), k=quad*8+j;  B lane n=l16(t), k=quad*8+j
//   D lane reg r: row(co)=quad*4+r, col(t)=l16   (validated rounds 3-8)
// ---------------------------------------------------------------------------
template <int COUT, int T, int KW, bool RELU, int CICH, int NC32T, int TP>
__device__ __forceinline__ void conv_body(const short* __restrict__ xT,
                                          const short* __restrict__ wp,
                                          const float* __restrict__ bias,
                                          short* __restrict__ outT,
                                          int bx, int by, int b) {
    constexpr int STRIDE = NC32T * 32;      // padded row width (shorts)
    constexpr int NC32 = CICH / 32;
    constexpr int NCHK = STRIDE / CICH;
    const int t0 = bx * 128, co0 = by * 64;
    const int tid = threadIdx.x, wave = tid >> 6, lane = tid & 63;
    const int quad = lane >> 4, l16 = lane & 15;
    const int wt = wave * 32;
    const int co16_0 = co0 >> 4;
    // lane's B-row base: row = t0+wt+ni*16+l16+k  (row index = t+PAD, guards zeroed)
    const short* xb = xT + ((size_t)b * TP + t0 + wt + l16) * STRIDE + quad * 8;

    floatx4 acc[4][2];
#pragma unroll
    for (int mi = 0; mi < 4; mi++)
#pragma unroll
        for (int ni = 0; ni < 2; ni++) acc[mi][ni] = (floatx4){0.f, 0.f, 0.f, 0.f};

    for (int kc = 0; kc < NCHK; kc++) {
#pragma unroll
        for (int k = 0; k < KW; k++) {
#pragma unroll
            for (int kk = 0; kk < NC32; kk++) {
                int ci32 = kc * NC32 + kk;
                short8 a[4];
#pragma unroll
                for (int mi = 0; mi < 4; mi++)
                    a[mi] = *(const short8*)(wp +
                        ((size_t)((co16_0 + mi) * KW + k) * NC32T + ci32) * 512 + lane * 8);
#pragma unroll
                for (int ni = 0; ni < 2; ni++) {
                    short8 bb = *(const short8*)(xb + (size_t)(ni * 16 + k) * STRIDE +
                                                 kc * CICH + kk * 32);
#pragma unroll
                    for (int mi = 0; mi < 4; mi++)
                        acc[mi][ni] = __builtin_amdgcn_mfma_f32_16x16x32_bf16(a[mi], bb,
                                                                              acc[mi][ni], 0, 0, 0);
                }
            }
        }
    }
#pragma unroll
    for (int mi = 0; mi < 4; mi++) {
        int cb = co0 + mi * 16 + quad * 4;
        if (cb < COUT) {
            float4 bv = *(const float4*)(bias + cb);
#pragma unroll
            for (int ni = 0; ni < 2; ni++) {
                int t = t0 + wt + ni * 16 + l16;
                if (t < T) {
                    float v0 = acc[mi][ni][0] + bv.x, v1 = acc[mi][ni][1] + bv.y;
                    float v2 = acc[mi][ni][2] + bv.z, v3 = acc[mi][ni][3] + bv.w;
                    if (RELU) {
                        v0 = fmaxf(v0, 0.f); v1 = fmaxf(v1, 0.f);
                        v2 = fmaxf(v2, 0.f); v3 = fmaxf(v3, 0.f);
                    }
                    ushort4 o;
                    o.x = (unsigned short)f2bf(v0); o.y = (unsigned short)f2bf(v1);
                    o.z = (unsigned short)f2bf(v2); o.w = (unsigned short)f2bf(v3);
                    *(ushort4*)(outT + ((size_t)b * T + t) * COUT + cb) = o;
                }
            }
        }
    }
}

// C: key conv3 (512 blocks) + query conv3 (384 blocks), no LDS, no barriers
__global__ __launch_bounds__(256, 3) void conv_kernel(
    const short* __restrict__ xkTp, const short* __restrict__ wk1p,
    const float* __restrict__ bk1, short* __restrict__ kh1T,
    const short* __restrict__ xqTp, const short* __restrict__ wq1p,
    const float* __restrict__ bq1, short* __restrict__ qh1T) {
    int bid = blockIdx.x;
    if (bid < 512) {
        int bx = bid & 1, by = (bid >> 1) & 15, b = bid >> 5;
        conv_body<C2T, T2, 3, true, 64, 16, TPK>(xkTp, wk1p, bk1, kh1T, bx, by, b);
    } else {
        int r = bid - 512;
        int bx = r & 7, by = (r >> 3) % 3, b = r / 24;
        conv_body<C2S, T1, 3, true, 96, 3, TPQ>(xqTp, wq1p, bq1, qh1T, bx, by, b);
    }
}

// ---------------------------------------------------------------------------
// key 1x1 GEMM (K=1024): A and B fragments straight from global, no LDS.
// Emits k_encT (stride ENC_STR, zero pad) + per-row k2.
// ---------------------------------------------------------------------------
__device__ __forceinline__ void kgemm_body(const short* __restrict__ xT,
                                           const short* __restrict__ wp,
                                           const float* __restrict__ bias,
                                           short* __restrict__ outT,
                                           float* __restrict__ k2ws, int bid) {
    const int n0 = bid * 64;
    const int tid = threadIdx.x, wave = tid >> 6, lane = tid & 63;
    const int quad = lane >> 4, l16 = lane & 15;
    const short* xrow = xT + (size_t)(n0 + wave * 16 + l16) * 1024 + quad * 8;
    floatx4 acc[5];
#pragma unroll
    for (int mi = 0; mi < 5; mi++) acc[mi] = (floatx4){0.f, 0.f, 0.f, 0.f};
    for (int kc = 0; kc < 8; kc++) {
#pragma unroll
        for (int kk = 0; kk < 4; kk++) {
            int ci32 = kc * 4 + kk;
            short8 bb = *(const short8*)(xrow + ci32 * 32);
#pragma unroll
            for (int mi = 0; mi < 5; mi++) {
                short8 a = *(const short8*)(wp + ((size_t)(mi * 32 + ci32)) * 512 + lane * 8);
                acc[mi] = __builtin_amdgcn_mfma_f32_16x16x32_bf16(a, bb, acc[mi], 0, 0, 0);
            }
        }
    }
    int n = n0 + wave * 16 + l16;
    float sq = 0.f;
#pragma unroll
    for (int mi = 0; mi < 5; mi++) {
        int cb = mi * 16 + quad * 4;
        float4 bv = *(const float4*)(bias + cb);
        float v0 = acc[mi][0] + bv.x, v1 = acc[mi][1] + bv.y;
        float v2 = acc[mi][2] + bv.z, v3 = acc[mi][3] + bv.w;
        sq += v0 * v0 + v1 * v1 + v2 * v2 + v3 * v3;
        ushort4 o;
        o.x = (unsigned short)f2bf(v0); o.y = (unsigned short)f2bf(v1);
        o.z = (unsigned short)f2bf(v2); o.w = (unsigned short)f2bf(v3);
        *(ushort4*)(outT + (size_t)n * ENC_STR + cb) = o;
    }
    if (quad < 2) *(uint4*)(outT + (size_t)n * ENC_STR + 80 + quad * 8) = (uint4){0u, 0u, 0u, 0u};
    sq += __shfl_xor(sq, 16, 64);
    sq += __shfl_xor(sq, 32, 64);
    if (quad == 0) k2ws[n] = sq;
}

// fused query conv2(relu)+conv3: X frags from global; H round-trips via LDS
__device__ __forceinline__ void qconv23_body(const short* __restrict__ h1,
                                             const short* __restrict__ w2p,
                                             const float* __restrict__ b2,
                                             const short* __restrict__ w3p,
                                             const float* __restrict__ b3,
                                             short* __restrict__ outT,
                                             short* Hs, int bid) {
    constexpr int P3 = 104;
    const int n0 = bid * 64;
    const int tid = threadIdx.x, wave = tid >> 6, lane = tid & 63;
    const int quad = lane >> 4, l16 = lane & 15;
    const short* xrow = h1 + (size_t)(n0 + wave * 16 + l16) * 160 + quad * 8;

    if (tid < 128) *(uint4*)(Hs + (tid >> 1) * P3 + 80 + (tid & 1) * 8) = (uint4){0u, 0u, 0u, 0u};

    floatx4 acc[5];
#pragma unroll
    for (int mi = 0; mi < 5; mi++) acc[mi] = (floatx4){0.f, 0.f, 0.f, 0.f};
#pragma unroll
    for (int kk = 0; kk < 5; kk++) {
        short8 bb = *(const short8*)(xrow + kk * 32);
#pragma unroll
        for (int mi = 0; mi < 5; mi++) {
            short8 a = *(const short8*)(w2p + ((size_t)(mi * 5 + kk)) * 512 + lane * 8);
            acc[mi] = __builtin_amdgcn_mfma_f32_16x16x32_bf16(a, bb, acc[mi], 0, 0, 0);
        }
    }
#pragma unroll
    for (int mi = 0; mi < 5; mi++) {
        int cb = mi * 16 + quad * 4;
        float4 bv = *(const float4*)(b2 + cb);
        ushort4 o;
        o.x = (unsigned short)f2bf(fmaxf(acc[mi][0] + bv.x, 0.f));
        o.y = (unsigned short)f2bf(fmaxf(acc[mi][1] + bv.y, 0.f));
        o.z = (unsigned short)f2bf(fmaxf(acc[mi][2] + bv.z, 0.f));
        o.w = (unsigned short)f2bf(fmaxf(acc[mi][3] + bv.w, 0.f));
        *(ushort4*)(Hs + (wave * 16 + l16) * P3 + cb) = o;
    }
    __syncthreads();

    floatx4 acc3[5];
#pragma unroll
    for (int mi = 0; mi < 5; mi++) acc3[mi] = (floatx4){0.f, 0.f, 0.f, 0.f};
#pragma unroll
    for (int kk = 0; kk < 3; kk++) {
        short8 bb = *(const short8*)(Hs + (wave * 16 + l16) * P3 + kk * 32 + quad * 8);
#pragma unroll
        for (int mi = 0; mi < 5; mi++) {
            short8 a = *(const short8*)(w3p + ((size_t)(mi * 3 + kk)) * 512 + lane * 8);
            acc3[mi] = __builtin_amdgcn_mfma_f32_16x16x32_bf16(a, bb, acc3[mi], 0, 0, 0);
        }
    }
    int n = n0 + wave * 16 + l16;
#pragma unroll
    for (int mi = 0; mi < 5; mi++) {
        int cb = mi * 16 + quad * 4;
        float4 bv = *(const float4*)(b3 + cb);
        ushort4 o;
        o.x = (unsigned short)f2bf(acc3[mi][0] + bv.x);
        o.y = (unsigned short)f2bf(acc3[mi][1] + bv.y);
        o.z = (unsigned short)f2bf(acc3[mi][2] + bv.z);
        o.w = (unsigned short)f2bf(acc3[mi][3] + bv.w);
        *(ushort4*)(outT + (size_t)n * ENC_STR + cb) = o;
    }
    if (quad < 2) *(uint4*)(outT + (size_t)n * ENC_STR + 80 + quad * 8) = (uint4){0u, 0u, 0u, 0u};
}

// G: key 1x1 GEMM (50 blocks) + fused query conv2+conv3 (250 blocks)
__global__ __launch_bounds__(256, 3) void gemm_kernel(
    const short* __restrict__ kh1T, const short* __restrict__ wk2p,
    const float* __restrict__ bk2, short* __restrict__ k_encT, float* __restrict__ k2ws,
    const short* __restrict__ qh1T, const short* __restrict__ wq2p,
    const float* __restrict__ bq2, const short* __restrict__ wq3p,
    const float* __restrict__ bq3, short* __restrict__ q_encT) {
    __shared__ short Hs[64 * 104];
    int bid = blockIdx.x;
    if (bid < 50) kgemm_body(kh1T, wk2p, bk2, k_encT, k2ws, bid);
    else qconv23_body(qh1T, wq2p, bq2, wq3p, bq3, q_encT, Hs, bid - 50);
}

// ---------------------------------------------------------------------------
// attention: LDS-free, barrier-free (validated round 8).
// ---------------------------------------------------------------------------
__device__ __forceinline__ float rmax16(float v) {
#pragma unroll
    for (int o = 1; o < 16; o <<= 1) v = fmaxf(v, __shfl_xor(v, o, 64));
    return v;
}
__device__ __forceinline__ float rsum16(float v) {
#pragma unroll
    for (int o = 1; o < 16; o <<= 1) v += __shfl_xor(v, o, 64);
    return v;
}

__global__ __launch_bounds__(256) void attn_kernel(const short* __restrict__ q_encT,
                                                   const short* __restrict__ k_encT,
                                                   const float* __restrict__ k2ws,
                                                   const float* __restrict__ prior,
                                                   const int* __restrict__ mask,
                                                   float* __restrict__ out_attn,
                                                   float* __restrict__ out_logp) {
    const int t10 = blockIdx.x * 64, b = blockIdx.y;
    const int tid = threadIdx.x, wave = tid >> 6, lane = tid & 63;
    const int quad = lane >> 4, l16 = lane & 15;

    float k2v[13]; int mskv[13];
#pragma unroll
    for (int n = 0; n < 13; n++) {
        int t2 = n * 16 + l16, t2c = t2 < T2 ? t2 : T2 - 1;
        k2v[n] = k2ws[b * T2 + t2c];
        mskv[n] = (t2 < T2) ? mask[b * T2 + t2] : 0;
    }
    const int t1base = t10 + wave * 16 + quad * 4;
    float pr[4][13];
#pragma unroll
    for (int r = 0; r < 4; r++) {
        int t1 = t1base + r, t1c = t1 < T1 ? t1 : T1 - 1;
#pragma unroll
        for (int n = 0; n < 13; n++) {
            int t2 = n * 16 + l16, t2c = t2 < T2 ? t2 : T2 - 1;
            pr[r][n] = prior[((size_t)b * T1 + t1c) * T2 + t2c];
        }
    }

    floatx4 acc[13];
#pragma unroll
    for (int n = 0; n < 13; n++) acc[n] = (floatx4){0.f, 0.f, 0.f, 0.f};
    const short* qb = q_encT + ((size_t)(b * T1 + t10 + wave * 16 + l16)) * ENC_STR + quad * 8;
    const short* kb = k_encT + ((size_t)(b * T2 + l16)) * ENC_STR + quad * 8;
#pragma unroll
    for (int kk = 0; kk < 3; kk++) {
        short8 a = *(const short8*)(qb + kk * 32);
#pragma unroll
        for (int n = 0; n < 13; n++) {
            short8 bb = *(const short8*)(kb + (size_t)n * 16 * ENC_STR + kk * 32);
            acc[n] = __builtin_amdgcn_mfma_f32_16x16x32_bf16(a, bb, acc[n], 0, 0, 0);
        }
    }

#pragma unroll
    for (int r = 0; r < 4; r++) {
        int t1 = t1base + r;
        bool t1ok = t1 < T1;
        float s[13], u[13];
        float mx = -INFINITY, mxu = -INFINITY;
#pragma unroll
        for (int n = 0; n < 13; n++) {
            int t2 = n * 16 + l16;
            float sv = (t2 < T2) ? TEMP_F * (2.f * acc[n][r] - k2v[n]) : -INFINITY;
            s[n] = sv;
            float uv = (t2 < T2) ? sv + __logf(pr[r][n] + 1e-8f) : -INFINITY;
            u[n] = uv;
            mx = fmaxf(mx, sv);
            mxu = fmaxf(mxu, (mskv[n] != 0) ? uv : -INFINITY);
        }
        float m = rmax16(mx);
        float m2 = rmax16(mxu);
        float se = 0.f, se2 = 0.f;
        float e2v[13];
#pragma unroll
        for (int n = 0; n < 13; n++) {
            se += (s[n] == -INFINITY) ? 0.f : __expf(s[n] - m);
            float e2 = (mskv[n] != 0) ? __expf(u[n] - m2) : 0.f;
            e2v[n] = e2;
            se2 += e2;
        }
        float logZ = __logf(rsum16(se));
        float invZ2 = 1.f / rsum16(se2);
        if (t1ok) {
#pragma unroll
            for (int n = 0; n < 13; n++) {
                int t2 = n * 16 + l16;
                if (t2 < T2) {
                    size_t o = ((size_t)b * T1 + t1) * T2 + t2;
                    out_attn[o] = e2v[n] * invZ2;
                    out_logp[o] = u[n] - m - logZ;
                }
            }
        }
    }
}

// ---------------------------------------------------------------------------
extern "C" void kernel_launch(void* const* d_in, const int* in_sizes, int n_in,
                              void* d_out, int out_size, void* d_ws, size_t ws_size,
                              hipStream_t stream) {
    const float* queries = (const float*)d_in[0];
    const float* keys    = (const float*)d_in[1];
    const int*   mask    = (const int*)d_in[2];
    const float* prior   = (const float*)d_in[3];
    const float* g       = (const float*)d_in[4];
    const float* wk1 = (const float*)d_in[5];
    const float* bk1 = (const float*)d_in[6];
    const float* wk2 = (const float*)d_in[7];
    const float* bk2 = (const float*)d_in[8];
    const float* wq1 = (const float*)d_in[9];
    const float* bq1 = (const float*)d_in[10];
    const float* wq2 = (const float*)d_in[11];
    const float* bq2 = (const float*)d_in[12];
    const float* wq3 = (const float*)d_in[13];
    const float* bq3 = (const float*)d_in[14];
    const float* w_kspk = (const float*)d_in[15];
    const float* b_kspk = (const float*)d_in[16];
    const float* w_qspk = (const float*)d_in[17];
    const float* b_qspk = (const float*)d_in[18];

    // ---- workspace layout (shorts) ----
    short* wsS   = (short*)d_ws;
    short* xkTp  = wsS;                              // 16x258x512        -> 2,113,536
    short* xqTp  = wsS + 2113536;                    // 16x1027x96        -> 3,691,008
    short* wk1p  = wsS + 3691008;                    // 3072 frags        -> 5,263,872
    short* wq1p  = wsS + 5263872;                    // 108 frags         -> 5,319,168
    short* wk2p  = wsS + 5319168;                    // 160 frags         -> 5,401,088
    short* wq2p  = wsS + 5401088;                    // 25 frags          -> 5,413,888
    short* wq3p  = wsS + 5413888;                    // 15 frags          -> 5,421,568
    short* k_encT = wsS + 5421568;                   // 3216x96           -> 5,730,304
    short* q_encT = wsS + 5730304;                   // 16032x96          -> 7,269,376
    float* k2ws  = (float*)d_ws + 3634688;           // 3200 fp32 (14.6 MB total)
    // hidden layers in d_out (consumed before attn overwrites):
    short* doS  = (short*)d_out;
    short* kh1T = doS;                               // 3200x1024 (6.55 MB)
    short* qh1T = doS + 3276800;                     // 16000x160 (5.12 MB)

    // P: all prep in one dispatch (2674 blocks)
    prep_kernel<<<dim3(2674), dim3(256), 0, stream>>>(
        keys, queries, g, wk1, wq1, wk2, wq2, wq3,
        w_kspk, b_kspk, w_qspk, b_qspk,
        wk1p, wq1p, wk2p, wq2p, wq3p, xkTp, xqTp);
    // C: both k=3 convs, fully LDS-free (896 blocks, 3 blocks/CU)
    conv_kernel<<<dim3(896), dim3(256), 0, stream>>>(xkTp, wk1p, bk1, kh1T,
                                                     xqTp, wq1p, bq1, qh1T);
    // G: key 1x1 GEMM (+k2) + fused query conv2/conv3 (300 blocks)
    gemm_kernel<<<dim3(300), dim3(256), 0, stream>>>(kh1T, wk2p, bk2, k_encT, k2ws,
                                                     qh1T, wq2p, bq2, wq3p, bq3, q_encT);
    // A: attention (LDS-free)
    float* out_attn = (float*)d_out;
    float* out_logp = out_attn + (size_t)NB * T1 * T2;
    attn_kernel<<<dim3(16, NB), dim3(256), 0, stream>>>(q_encT, k_encT, k2ws, prior, mask,
                                                        out_attn, out_logp);
}